// Round 1
// baseline (5897.757 us; speedup 1.0000x reference)
//
#include <hip/hip_runtime.h>
#include <math.h>

#define BB 32
#define HH 512
#define VV 32000
#define TT 64
#define NTILE 1000

// Workspace layout (float offsets)
#define OFF_H0T   0        // 2 x [512][32]
#define OFF_H1T   32768    // 2 x [512][32]
#define OFF_C0    65536    // [hu][b] 512x32
#define OFF_C1    81920
#define OFF_PC0   98304    // [2048][32]  ctx-part of L0 gates + biases
#define OFF_AMAX  163840   // 32 x unsigned long long
#define OFF_PAIRS 163904   // [64][1000][64] floats: per-tile (m[32], s[32]) = 16.4 MB

typedef float f32x4_ __attribute__((ext_vector_type(4)));

__device__ __forceinline__ float sigmoidf_(float x) { return 1.0f / (1.0f + expf(-x)); }

__device__ __forceinline__ float dot4(const float4 wv, const float4 xv) {
    return wv.x * xv.x + wv.y * xv.y + wv.z * xv.z + wv.w * xv.w;
}
__device__ __forceinline__ void bcast_fma(float* A, const float4 wv,
                                          const float4 x0, const float4 x1,
                                          const float4 x2, const float4 x3) {
    A[0] += wv.x * x0.x + wv.y * x1.x + wv.z * x2.x + wv.w * x3.x;
    A[1] += wv.x * x0.y + wv.y * x1.y + wv.z * x2.y + wv.w * x3.y;
    A[2] += wv.x * x0.z + wv.y * x1.z + wv.z * x2.z + wv.w * x3.z;
    A[3] += wv.x * x0.w + wv.y * x1.w + wv.z * x2.w + wv.w * x3.w;
}

// ---------------------------------------------------------------------------
__global__ void k_init(float* __restrict__ ws) {
    int idx = blockIdx.x * 256 + threadIdx.x;   // 64 x 256 = 16384
    ws[OFF_H0T + idx] = 0.0f;   // h0T buffer 0
    ws[OFF_H1T + idx] = 0.0f;   // h1T buffer 0
    ws[OFF_C0 + idx]  = 0.0f;
    ws[OFF_C1 + idx]  = 0.0f;
    if (idx < BB) ((unsigned long long*)(ws + OFF_AMAX))[idx] = 0xFFFFFFFEull; // tok=1
}

// ---------------------------------------------------------------------------
// pc0[r][b] = sum_k Wih0[r][512+k]*ctx[b][k] + bih0[r] + bhh0[r]
// grid 128 blocks (4 hu each) x 256 threads: ks16 x bg4(B=8) x rg4(hu)
// ---------------------------------------------------------------------------
__global__ __launch_bounds__(256, 4) void k_pc0(
    const float* __restrict__ Wih0, const float* __restrict__ ctx,
    const float* __restrict__ bih0, const float* __restrict__ bhh0,
    float* __restrict__ pc0)
{
    __shared__ float red[16][16][32];
    const int tid = threadIdx.x;
    const int ks = tid >> 4, bg = (tid >> 2) & 3, rg = tid & 3;
    const int hu = blockIdx.x * 4 + rg;
    const int k0 = ks * 32, b0 = bg * 8;

    float acc[4][8];
#pragma unroll
    for (int g = 0; g < 4; ++g)
#pragma unroll
        for (int j = 0; j < 8; ++j) acc[g][j] = 0.0f;

    const float* wp[4];
#pragma unroll
    for (int g = 0; g < 4; ++g) wp[g] = Wih0 + (size_t)(g * 512 + hu) * 1024 + 512 + k0;

#pragma unroll 2
    for (int kk4 = 0; kk4 < 8; ++kk4) {
        const int kk = kk4 * 4;
        float4 w4[4];
#pragma unroll
        for (int g = 0; g < 4; ++g) w4[g] = *(const float4*)(wp[g] + kk);
#pragma unroll
        for (int j = 0; j < 8; ++j) {
            const float4 xe = *(const float4*)(ctx + (size_t)(b0 + j) * 512 + k0 + kk);
#pragma unroll
            for (int g = 0; g < 4; ++g) acc[g][j] += dot4(w4[g], xe);
        }
    }

#pragma unroll
    for (int g = 0; g < 4; ++g) {
        *(float4*)&red[ks][g * 4 + rg][b0]     = make_float4(acc[g][0], acc[g][1], acc[g][2], acc[g][3]);
        *(float4*)&red[ks][g * 4 + rg][b0 + 4] = make_float4(acc[g][4], acc[g][5], acc[g][6], acc[g][7]);
    }
    __syncthreads();
    if (tid < 128) {
        const int huL = (tid >> 5) & 3, b = tid & 31;
#pragma unroll
        for (int g = 0; g < 4; ++g) {
            float s = 0.0f;
#pragma unroll
            for (int k = 0; k < 16; ++k) s += red[k][g * 4 + huL][b];
            const int row = g * 512 + blockIdx.x * 4 + huL;
            pc0[(size_t)row * 32 + b] = s + bih0[row] + bhh0[row];
        }
    }
}

// ---------------------------------------------------------------------------
// LSTM layer. gates[r][b] = sum_kA Wa[r][kA]*xA[kA][b] + sum_kB Wb[r][kB]*xB[kB][b]
// MODE0: xA = emb[tok[b]] (gather, k-contig), xB = h0T_prev; + pc0
// MODE1: xA = h0T_new (bcast [k][b]),        xB = h1T_prev; + biases
// grid 512 blocks (1 hu each) x 256 threads: ks32(K=32) x bg8(B=4)
// (2 blocks/CU -> 2 waves/SIMD for latency hiding; was 1)
// ---------------------------------------------------------------------------
template <int MODE>
__global__ __launch_bounds__(256, 4) void k_lstm(
    const float* __restrict__ Wa, const float* __restrict__ Wb,
    const float* __restrict__ xA, const float* __restrict__ xB,
    const float* __restrict__ emb,
    const unsigned long long* __restrict__ amax_in,
    const float* __restrict__ pc0,
    const float* __restrict__ bih, const float* __restrict__ bhh,
    float* __restrict__ hT_out, float* __restrict__ c_st,
    unsigned long long* __restrict__ amax_reset)
{
    constexpr int SA = (MODE == 0) ? 1024 : 512;   // Wa row stride
    __shared__ float red[32][4][32];
    __shared__ float gg[4][32];

    const int tid = threadIdx.x;
    const int ks = tid >> 3, bg = tid & 7;
    const int hu = blockIdx.x;
    const int b0 = bg * 4;
    const bool partA = (ks < 16);          // wave-uniform (8 consecutive ks per wave)
    const int k0 = (partA ? ks : ks - 16) * 32;

    float acc[4][4];
#pragma unroll
    for (int g = 0; g < 4; ++g)
#pragma unroll
        for (int j = 0; j < 4; ++j) acc[g][j] = 0.0f;

    const float* wp[4];
#pragma unroll
    for (int g = 0; g < 4; ++g)
        wp[g] = partA ? (Wa + (size_t)(g * 512 + hu) * SA + k0)
                      : (Wb + (size_t)(g * 512 + hu) * 512 + k0);

    const float* ep[4];
    if (MODE == 0 && partA) {
#pragma unroll
        for (int j = 0; j < 4; ++j) {
            const int tok = (int)(0xFFFFFFFFu - (unsigned)(amax_in[b0 + j] & 0xFFFFFFFFull));
            ep[j] = emb + (size_t)tok * 512 + k0;
        }
    }
    const float* xb = (partA ? xA : xB) + (size_t)k0 * 32 + b0;

#pragma unroll 4
    for (int kk4 = 0; kk4 < 8; ++kk4) {
        const int kk = kk4 * 4;
        float4 w4[4];
#pragma unroll
        for (int g = 0; g < 4; ++g) w4[g] = *(const float4*)(wp[g] + kk);
        if (MODE == 0 && partA) {
#pragma unroll
            for (int j = 0; j < 4; ++j) {
                const float4 xe = *(const float4*)(ep[j] + kk);
#pragma unroll
                for (int g = 0; g < 4; ++g) acc[g][j] += dot4(w4[g], xe);
            }
        } else {
            const float4 x0 = *(const float4*)(xb + (size_t)(kk + 0) * 32);
            const float4 x1 = *(const float4*)(xb + (size_t)(kk + 1) * 32);
            const float4 x2 = *(const float4*)(xb + (size_t)(kk + 2) * 32);
            const float4 x3 = *(const float4*)(xb + (size_t)(kk + 3) * 32);
#pragma unroll
            for (int g = 0; g < 4; ++g) bcast_fma(acc[g], w4[g], x0, x1, x2, x3);
        }
    }

#pragma unroll
    for (int g = 0; g < 4; ++g)
        *(float4*)&red[ks][g][b0] = make_float4(acc[g][0], acc[g][1], acc[g][2], acc[g][3]);
    __syncthreads();

    if (tid < 128) {
        const int g = tid >> 5, b = tid & 31;
        float s = 0.0f;
#pragma unroll
        for (int k = 0; k < 32; ++k) s += red[k][g][b];
        const int row = g * 512 + hu;
        if (MODE == 0) s += pc0[(size_t)row * 32 + b];
        else           s += bih[row] + bhh[row];
        gg[g][b] = s;
    }
    __syncthreads();

    if (tid < 32) {
        const int b = tid;
        const float gi = sigmoidf_(gg[0][b]);
        const float gf = sigmoidf_(gg[1][b]);
        const float gn = tanhf(gg[2][b]);
        const float go = sigmoidf_(gg[3][b]);
        const int ci = hu * 32 + b;
        const float cn = gf * c_st[ci] + gi * gn;
        c_st[ci] = cn;
        hT_out[ci] = go * tanhf(cn);
    }
    if (MODE == 1) {
        if (tid >= 64 && tid < 96) amax_reset[tid - 64] = 0ull;
    }
}

// ---------------------------------------------------------------------------
// logits[row][b] = h1 . Wout[row] + bout[row]; write out[b][t][row]; argmax;
// also per-tile (max, sum-exp) partials for the final log-softmax.
// grid 1000 blocks (32 rows) x 256 threads: ks8(K=64) x bg4(B=8) x rg8(R=4)
// ---------------------------------------------------------------------------
__global__ __launch_bounds__(256, 4) void k_logits(
    const float* __restrict__ h1T, const float* __restrict__ Wout,
    const float* __restrict__ bout, float* __restrict__ out,
    unsigned long long* __restrict__ amax, float* __restrict__ pairs, int t)
{
    __shared__ float red[8][32][35];
    __shared__ unsigned long long lmax[8][32];
    __shared__ float pm[8][32], ps[8][32];

    const int tid = threadIdx.x;
    const int rg = tid & 7, bg = (tid >> 3) & 3, ks = tid >> 5;
    const int row0 = blockIdx.x * 32 + rg * 4;
    const int b0 = bg * 8, k0 = ks * 64;

    float acc[4][8];
#pragma unroll
    for (int i = 0; i < 4; ++i)
#pragma unroll
        for (int j = 0; j < 8; ++j) acc[i][j] = 0.0f;

    const float* wp[4];
#pragma unroll
    for (int i = 0; i < 4; ++i) wp[i] = Wout + (size_t)(row0 + i) * 512 + k0;
    const float* xb = h1T + (size_t)k0 * 32 + b0;

#pragma unroll 2
    for (int kk4 = 0; kk4 < 16; ++kk4) {
        const int kk = kk4 * 4;
        const float4 x00 = *(const float4*)(xb + (size_t)(kk + 0) * 32);
        const float4 x01 = *(const float4*)(xb + (size_t)(kk + 0) * 32 + 4);
        const float4 x10 = *(const float4*)(xb + (size_t)(kk + 1) * 32);
        const float4 x11 = *(const float4*)(xb + (size_t)(kk + 1) * 32 + 4);
        const float4 x20 = *(const float4*)(xb + (size_t)(kk + 2) * 32);
        const float4 x21 = *(const float4*)(xb + (size_t)(kk + 2) * 32 + 4);
        const float4 x30 = *(const float4*)(xb + (size_t)(kk + 3) * 32);
        const float4 x31 = *(const float4*)(xb + (size_t)(kk + 3) * 32 + 4);
#pragma unroll
        for (int i = 0; i < 4; ++i) {
            const float4 w = *(const float4*)(wp[i] + kk);
            bcast_fma(&acc[i][0], w, x00, x10, x20, x30);
            bcast_fma(&acc[i][4], w, x01, x11, x21, x31);
        }
    }

#pragma unroll
    for (int i = 0; i < 4; ++i) {
        *(float4*)&red[ks][rg * 4 + i][b0]     = make_float4(acc[i][0], acc[i][1], acc[i][2], acc[i][3]);
        *(float4*)&red[ks][rg * 4 + i][b0 + 4] = make_float4(acc[i][4], acc[i][5], acc[i][6], acc[i][7]);
    }
    __syncthreads();

    // (a) coalesced non-temporal stores (out is write-once, read much later)
    {
        const int r2 = tid & 31, bq = tid >> 5;
        const int row = blockIdx.x * 32 + r2;
        const float bias = bout[row];
#pragma unroll
        for (int j = 0; j < 4; ++j) {
            const int b = bq * 4 + j;
            float v = bias;
#pragma unroll
            for (int k = 0; k < 8; ++k) v += red[k][r2][b];
            __builtin_nontemporal_store(v, out + ((size_t)b * TT + t) * VV + row);
        }
    }
    // (b) per-batch argmax candidates + per-tile (m, s) partials
    {
        const int b = tid & 31, rq = tid >> 5;
        unsigned long long best = 0ull;
        float vv[4];
#pragma unroll
        for (int i = 0; i < 4; ++i) {
            const int rr = rq * 4 + i;
            const int row = blockIdx.x * 32 + rr;
            float v = bout[row];
#pragma unroll
            for (int k = 0; k < 8; ++k) v += red[k][rr][b];
            vv[i] = v;
            unsigned u = __float_as_uint(v);
            u = (u & 0x80000000u) ? ~u : (u | 0x80000000u);
            const unsigned long long key =
                ((unsigned long long)u << 32) | (unsigned long long)(0xFFFFFFFFu - (unsigned)row);
            best = best > key ? best : key;
        }
        lmax[rq][b] = best;
        const float lm = fmaxf(fmaxf(vv[0], vv[1]), fmaxf(vv[2], vv[3]));
        ps[rq][b] = __expf(vv[0] - lm) + __expf(vv[1] - lm)
                  + __expf(vv[2] - lm) + __expf(vv[3] - lm);
        pm[rq][b] = lm;
    }
    __syncthreads();
    if (tid < 32) {
        unsigned long long bb = lmax[0][tid];
#pragma unroll
        for (int q = 1; q < 8; ++q) bb = bb > lmax[q][tid] ? bb : lmax[q][tid];
        if (bb > amax[tid]) atomicMax(&amax[tid], bb);
        if (pairs) {
            float M = pm[0][tid], S = ps[0][tid];
#pragma unroll
            for (int q = 1; q < 8; ++q) {
                const float nm = fmaxf(M, pm[q][tid]);
                S = S * __expf(M - nm) + ps[q][tid] * __expf(pm[q][tid] - nm);
                M = nm;
            }
            float* pr = pairs + ((size_t)t * NTILE + blockIdx.x) * 64;
            pr[tid] = M;
            pr[32 + tid] = S;
        }
    }
}

// ---------------------------------------------------------------------------
// log-softmax. With pairs: combine 1000 per-tile (m,s) (8 KB) then ONE
// read+subtract+write sweep. Without: original fused 2-sweep fallback.
// ---------------------------------------------------------------------------
__global__ __launch_bounds__(256) void k_lsm(float* __restrict__ out,
                                             const float* __restrict__ pairs) {
    float* p = out + (size_t)blockIdx.x * VV;
    const int tid = threadIdx.x;
    __shared__ float sm[4], ss[4];

    float m = -1e30f, s = 0.0f;
    if (pairs) {
        const int b = blockIdx.x >> 6, t = blockIdx.x & 63;
        const float* pr = pairs + (size_t)t * NTILE * 64 + b;
        for (int tile = tid; tile < NTILE; tile += 256) {
            const float tm = pr[(size_t)tile * 64];
            const float ts = pr[(size_t)tile * 64 + 32];
            const float nm = fmaxf(m, tm);
            s = s * __expf(m - nm) + ts * __expf(tm - nm);
            m = nm;
        }
    } else {
        for (int i = tid * 4; i < VV; i += 1024) {
            const float4 v = *(const float4*)(p + i);
            const float cm = fmaxf(fmaxf(v.x, v.y), fmaxf(v.z, v.w));
            const float nm = fmaxf(m, cm);
            s = s * __expf(m - nm) + __expf(v.x - nm) + __expf(v.y - nm)
                                   + __expf(v.z - nm) + __expf(v.w - nm);
            m = nm;
        }
    }
#pragma unroll
    for (int off = 32; off > 0; off >>= 1) {
        const float om = __shfl_down(m, off, 64);
        const float os = __shfl_down(s, off, 64);
        const float nm = fmaxf(m, om);
        s = s * __expf(m - nm) + os * __expf(om - nm);
        m = nm;
    }
    if ((tid & 63) == 0) { sm[tid >> 6] = m; ss[tid >> 6] = s; }
    __syncthreads();
    float M = sm[0], S = ss[0];
#pragma unroll
    for (int w = 1; w < 4; ++w) {
        const float nm = fmaxf(M, sm[w]);
        S = S * __expf(M - nm) + ss[w] * __expf(sm[w] - nm);
        M = nm;
    }
    const float lz = M + __logf(S);
    for (int i = tid * 4; i < VV; i += 1024) {
        f32x4_ v = *(const f32x4_*)(p + i);
        v = v - lz;
        __builtin_nontemporal_store(v, (f32x4_*)(p + i));
    }
}

// ---------------------------------------------------------------------------
extern "C" void kernel_launch(void* const* d_in, const int* in_sizes, int n_in,
                              void* d_out, int out_size, void* d_ws, size_t ws_size,
                              hipStream_t stream) {
    const float* ctx  = (const float*)d_in[0];
    const float* emb  = (const float*)d_in[1];
    const float* Wih0 = (const float*)d_in[2];
    const float* Whh0 = (const float*)d_in[3];
    const float* bih0 = (const float*)d_in[4];
    const float* bhh0 = (const float*)d_in[5];
    const float* Wih1 = (const float*)d_in[6];
    const float* Whh1 = (const float*)d_in[7];
    const float* bih1 = (const float*)d_in[8];
    const float* bhh1 = (const float*)d_in[9];
    const float* Wout = (const float*)d_in[10];
    const float* bout = (const float*)d_in[11];

    float* out = (float*)d_out;
    float* ws  = (float*)d_ws;
    float* h0T[2] = { ws + OFF_H0T, ws + OFF_H0T + 16384 };
    float* h1T[2] = { ws + OFF_H1T, ws + OFF_H1T + 16384 };
    float* c0  = ws + OFF_C0;
    float* c1  = ws + OFF_C1;
    float* pc0 = ws + OFF_PC0;
    unsigned long long* amax = (unsigned long long*)(ws + OFF_AMAX);

    const size_t need_bytes = (size_t)(OFF_PAIRS + TT * NTILE * 64) * sizeof(float);
    float* pairs = (ws_size >= need_bytes) ? (ws + OFF_PAIRS) : nullptr;

    k_init<<<64, 256, 0, stream>>>(ws);
    k_pc0<<<128, 256, 0, stream>>>(Wih0, ctx, bih0, bhh0, pc0);

    for (int t = 0; t < TT; ++t) {
        const int pp = t & 1, nn = pp ^ 1;
        k_lstm<0><<<512, 256, 0, stream>>>(
            Wih0, Whh0, nullptr, h0T[pp], emb, amax, pc0, nullptr, nullptr,
            h0T[nn], c0, nullptr);
        k_lstm<1><<<512, 256, 0, stream>>>(
            Wih1, Whh1, h0T[nn], h1T[pp], emb, nullptr, nullptr, bih1, bhh1,
            h1T[nn], c1, amax);
        k_logits<<<1000, 256, 0, stream>>>(h1T[nn], Wout, bout, out, amax, pairs, t);
    }
    k_lsm<<<BB * TT, 256, 0, stream>>>(out, pairs);
}

// Round 2
// 5451.710 us; speedup vs baseline: 1.0818x; 1.0818x over previous
//
#include <hip/hip_runtime.h>
#include <math.h>

#define BB 32
#define HH 512
#define VV 32000
#define TT 64
#define NTILE 1000

// Workspace layout (float offsets)
#define OFF_H0T   0        // 2 x [512][32]
#define OFF_H1T   32768    // 2 x [512][32]
#define OFF_C0    65536    // [hu][b] 512x32
#define OFF_C1    81920
#define OFF_PC0   98304    // [2048][32]  ctx-part of L0 gates + biases
#define OFF_AMAX  163840   // 32 x unsigned long long
#define OFF_PAIRS 163904   // [64][1000][64] floats: per-tile (m[32], s[32]) = 16.4 MB

typedef float f32x4_ __attribute__((ext_vector_type(4)));

__device__ __forceinline__ float sigmoidf_(float x) { return 1.0f / (1.0f + expf(-x)); }

__device__ __forceinline__ float dot4(const float4 wv, const float4 xv) {
    return wv.x * xv.x + wv.y * xv.y + wv.z * xv.z + wv.w * xv.w;
}
__device__ __forceinline__ void bcast_fma(float* A, const float4 wv,
                                          const float4 x0, const float4 x1,
                                          const float4 x2, const float4 x3) {
    A[0] += wv.x * x0.x + wv.y * x1.x + wv.z * x2.x + wv.w * x3.x;
    A[1] += wv.x * x0.y + wv.y * x1.y + wv.z * x2.y + wv.w * x3.y;
    A[2] += wv.x * x0.z + wv.y * x1.z + wv.z * x2.z + wv.w * x3.z;
    A[3] += wv.x * x0.w + wv.y * x1.w + wv.z * x2.w + wv.w * x3.w;
}

// ---------------------------------------------------------------------------
__global__ void k_init(float* __restrict__ ws) {
    int idx = blockIdx.x * 256 + threadIdx.x;   // 64 x 256 = 16384
    ws[OFF_H0T + idx] = 0.0f;   // h0T buffer 0
    ws[OFF_H1T + idx] = 0.0f;   // h1T buffer 0
    ws[OFF_C0 + idx]  = 0.0f;
    ws[OFF_C1 + idx]  = 0.0f;
    if (idx < BB) ((unsigned long long*)(ws + OFF_AMAX))[idx] = 0xFFFFFFFEull; // tok=1
}

// ---------------------------------------------------------------------------
// pc0[r][b] = sum_k Wih0[r][512+k]*ctx[b][k] + bih0[r] + bhh0[r]
// grid 128 blocks (4 hu each) x 256 threads: ks16 x bg4(B=8) x rg4(hu)
// ---------------------------------------------------------------------------
__global__ __launch_bounds__(256, 4) void k_pc0(
    const float* __restrict__ Wih0, const float* __restrict__ ctx,
    const float* __restrict__ bih0, const float* __restrict__ bhh0,
    float* __restrict__ pc0)
{
    __shared__ float red[16][16][32];
    const int tid = threadIdx.x;
    const int ks = tid >> 4, bg = (tid >> 2) & 3, rg = tid & 3;
    const int hu = blockIdx.x * 4 + rg;
    const int k0 = ks * 32, b0 = bg * 8;

    float acc[4][8];
#pragma unroll
    for (int g = 0; g < 4; ++g)
#pragma unroll
        for (int j = 0; j < 8; ++j) acc[g][j] = 0.0f;

    const float* wp[4];
#pragma unroll
    for (int g = 0; g < 4; ++g) wp[g] = Wih0 + (size_t)(g * 512 + hu) * 1024 + 512 + k0;

#pragma unroll 2
    for (int kk4 = 0; kk4 < 8; ++kk4) {
        const int kk = kk4 * 4;
        float4 w4[4];
#pragma unroll
        for (int g = 0; g < 4; ++g) w4[g] = *(const float4*)(wp[g] + kk);
#pragma unroll
        for (int j = 0; j < 8; ++j) {
            const float4 xe = *(const float4*)(ctx + (size_t)(b0 + j) * 512 + k0 + kk);
#pragma unroll
            for (int g = 0; g < 4; ++g) acc[g][j] += dot4(w4[g], xe);
        }
    }

#pragma unroll
    for (int g = 0; g < 4; ++g) {
        *(float4*)&red[ks][g * 4 + rg][b0]     = make_float4(acc[g][0], acc[g][1], acc[g][2], acc[g][3]);
        *(float4*)&red[ks][g * 4 + rg][b0 + 4] = make_float4(acc[g][4], acc[g][5], acc[g][6], acc[g][7]);
    }
    __syncthreads();
    if (tid < 128) {
        const int huL = (tid >> 5) & 3, b = tid & 31;
#pragma unroll
        for (int g = 0; g < 4; ++g) {
            float s = 0.0f;
#pragma unroll
            for (int k = 0; k < 16; ++k) s += red[k][g * 4 + huL][b];
            const int row = g * 512 + blockIdx.x * 4 + huL;
            pc0[(size_t)row * 32 + b] = s + bih0[row] + bhh0[row];
        }
    }
}

// ---------------------------------------------------------------------------
// LSTM layer. gates[r][b] = sum_kA Wa[r][kA]*xA[kA][b] + sum_kB Wb[r][kB]*xB[kB][b]
// MODE0: xA = emb[tok[b]] (gather, k-contig), xB = h0T_prev; + pc0
// MODE1: xA = h0T_new (bcast [k][b]),        xB = h1T_prev; + biases
// grid 256 blocks (2 hu) x 256 threads: ks16(K=64) x bg8(B=4) x rg2(hu)
// (round-0 structure restored: round-1's 512x(1hu) variant regressed ~+3.7us/dispatch)
// ---------------------------------------------------------------------------
template <int MODE>
__global__ __launch_bounds__(256, 4) void k_lstm(
    const float* __restrict__ Wa, const float* __restrict__ Wb,
    const float* __restrict__ xA, const float* __restrict__ xB,
    const float* __restrict__ emb,
    const unsigned long long* __restrict__ amax_in,
    const float* __restrict__ pc0,
    const float* __restrict__ bih, const float* __restrict__ bhh,
    float* __restrict__ hT_out, float* __restrict__ c_st,
    unsigned long long* __restrict__ amax_reset)
{
    constexpr int SA = (MODE == 0) ? 1024 : 512;   // Wa row stride
    __shared__ float red[16][8][32];

    const int tid = threadIdx.x;
    const int ks = tid >> 4, bg = (tid >> 1) & 7, rg = tid & 1;
    const int hu = blockIdx.x * 2 + rg;
    const int b0 = bg * 4;
    const bool partA = (ks < 8);           // wave-uniform (wave = 4 consecutive ks)
    const int k0 = (partA ? ks : ks - 8) * 64;

    float acc[4][4];
#pragma unroll
    for (int g = 0; g < 4; ++g)
#pragma unroll
        for (int j = 0; j < 4; ++j) acc[g][j] = 0.0f;

    const float* wp[4];
#pragma unroll
    for (int g = 0; g < 4; ++g)
        wp[g] = partA ? (Wa + (size_t)(g * 512 + hu) * SA + k0)
                      : (Wb + (size_t)(g * 512 + hu) * 512 + k0);

    const float* ep[4];
    if (MODE == 0 && partA) {
#pragma unroll
        for (int j = 0; j < 4; ++j) {
            const int tok = (int)(0xFFFFFFFFu - (unsigned)(amax_in[b0 + j] & 0xFFFFFFFFull));
            ep[j] = emb + (size_t)tok * 512 + k0;
        }
    }
    const float* xb = (partA ? xA : xB) + (size_t)k0 * 32 + b0;

#pragma unroll 2
    for (int kk4 = 0; kk4 < 16; ++kk4) {
        const int kk = kk4 * 4;
        float4 w4[4];
#pragma unroll
        for (int g = 0; g < 4; ++g) w4[g] = *(const float4*)(wp[g] + kk);
        if (MODE == 0 && partA) {
#pragma unroll
            for (int j = 0; j < 4; ++j) {
                const float4 xe = *(const float4*)(ep[j] + kk);
#pragma unroll
                for (int g = 0; g < 4; ++g) acc[g][j] += dot4(w4[g], xe);
            }
        } else {
            const float4 x0 = *(const float4*)(xb + (size_t)(kk + 0) * 32);
            const float4 x1 = *(const float4*)(xb + (size_t)(kk + 1) * 32);
            const float4 x2 = *(const float4*)(xb + (size_t)(kk + 2) * 32);
            const float4 x3 = *(const float4*)(xb + (size_t)(kk + 3) * 32);
#pragma unroll
            for (int g = 0; g < 4; ++g) bcast_fma(acc[g], w4[g], x0, x1, x2, x3);
        }
    }

#pragma unroll
    for (int g = 0; g < 4; ++g)
        *(float4*)&red[ks][g * 2 + rg][b0] = make_float4(acc[g][0], acc[g][1], acc[g][2], acc[g][3]);
    __syncthreads();

    if (tid < 64) {
        const int huL = tid >> 5, b = tid & 31;
        const int hu2 = blockIdx.x * 2 + huL;
        float gate[4];
#pragma unroll
        for (int g = 0; g < 4; ++g) {
            float s = 0.0f;
#pragma unroll
            for (int k = 0; k < 16; ++k) s += red[k][g * 2 + huL][b];
            const int row = g * 512 + hu2;
            if (MODE == 0) s += pc0[(size_t)row * 32 + b];
            else           s += bih[row] + bhh[row];
            gate[g] = s;
        }
        const float gi = sigmoidf_(gate[0]);
        const float gf = sigmoidf_(gate[1]);
        const float gg = tanhf(gate[2]);
        const float go = sigmoidf_(gate[3]);
        const int ci = hu2 * 32 + b;
        const float cn = gf * c_st[ci] + gi * gg;
        c_st[ci] = cn;
        hT_out[ci] = go * tanhf(cn);
    }
    if (MODE == 1) {
        if (tid >= 64 && tid < 96) amax_reset[tid - 64] = 0ull;
    }
}

// ---------------------------------------------------------------------------
// logits[row][b] = h1 . Wout[row] + bout[row]; write out[b][t][row]; argmax;
// also per-tile (max, sum-exp) partials for the final log-softmax.
// grid 1000 blocks (32 rows) x 256 threads: ks8(K=64) x bg4(B=8) x rg8(R=4)
// (round-0 structure: red stride 36, plain stores; only pairs epilogue added)
// ---------------------------------------------------------------------------
__global__ __launch_bounds__(256, 4) void k_logits(
    const float* __restrict__ h1T, const float* __restrict__ Wout,
    const float* __restrict__ bout, float* __restrict__ out,
    unsigned long long* __restrict__ amax, float* __restrict__ pairs, int t)
{
    __shared__ float red[8][32][36];
    __shared__ unsigned long long lmax[8][32];
    __shared__ float pm[8][32], ps[8][32];

    const int tid = threadIdx.x;
    const int rg = tid & 7, bg = (tid >> 3) & 3, ks = tid >> 5;
    const int row0 = blockIdx.x * 32 + rg * 4;
    const int b0 = bg * 8, k0 = ks * 64;

    float acc[4][8];
#pragma unroll
    for (int i = 0; i < 4; ++i)
#pragma unroll
        for (int j = 0; j < 8; ++j) acc[i][j] = 0.0f;

    const float* wp[4];
#pragma unroll
    for (int i = 0; i < 4; ++i) wp[i] = Wout + (size_t)(row0 + i) * 512 + k0;
    const float* xb = h1T + (size_t)k0 * 32 + b0;

#pragma unroll 2
    for (int kk4 = 0; kk4 < 16; ++kk4) {
        const int kk = kk4 * 4;
        const float4 x00 = *(const float4*)(xb + (size_t)(kk + 0) * 32);
        const float4 x01 = *(const float4*)(xb + (size_t)(kk + 0) * 32 + 4);
        const float4 x10 = *(const float4*)(xb + (size_t)(kk + 1) * 32);
        const float4 x11 = *(const float4*)(xb + (size_t)(kk + 1) * 32 + 4);
        const float4 x20 = *(const float4*)(xb + (size_t)(kk + 2) * 32);
        const float4 x21 = *(const float4*)(xb + (size_t)(kk + 2) * 32 + 4);
        const float4 x30 = *(const float4*)(xb + (size_t)(kk + 3) * 32);
        const float4 x31 = *(const float4*)(xb + (size_t)(kk + 3) * 32 + 4);
#pragma unroll
        for (int i = 0; i < 4; ++i) {
            const float4 w = *(const float4*)(wp[i] + kk);
            bcast_fma(&acc[i][0], w, x00, x10, x20, x30);
            bcast_fma(&acc[i][4], w, x01, x11, x21, x31);
        }
    }

#pragma unroll
    for (int i = 0; i < 4; ++i) {
        *(float4*)&red[ks][rg * 4 + i][b0]     = make_float4(acc[i][0], acc[i][1], acc[i][2], acc[i][3]);
        *(float4*)&red[ks][rg * 4 + i][b0 + 4] = make_float4(acc[i][4], acc[i][5], acc[i][6], acc[i][7]);
    }
    __syncthreads();

    // (a) coalesced stores
    {
        const int r2 = tid & 31, bq = tid >> 5;
        const int row = blockIdx.x * 32 + r2;
        const float bias = bout[row];
#pragma unroll
        for (int j = 0; j < 4; ++j) {
            const int b = bq * 4 + j;
            float v = bias;
#pragma unroll
            for (int k = 0; k < 8; ++k) v += red[k][r2][b];
            out[((size_t)b * TT + t) * VV + row] = v;
        }
    }
    // (b) per-batch argmax candidates + per-tile (m, s) partials
    {
        const int b = tid & 31, rq = tid >> 5;
        unsigned long long best = 0ull;
        float vv[4];
#pragma unroll
        for (int i = 0; i < 4; ++i) {
            const int rr = rq * 4 + i;
            const int row = blockIdx.x * 32 + rr;
            float v = bout[row];
#pragma unroll
            for (int k = 0; k < 8; ++k) v += red[k][rr][b];
            vv[i] = v;
            unsigned u = __float_as_uint(v);
            u = (u & 0x80000000u) ? ~u : (u | 0x80000000u);
            const unsigned long long key =
                ((unsigned long long)u << 32) | (unsigned long long)(0xFFFFFFFFu - (unsigned)row);
            best = best > key ? best : key;
        }
        lmax[rq][b] = best;
        const float lm = fmaxf(fmaxf(vv[0], vv[1]), fmaxf(vv[2], vv[3]));
        ps[rq][b] = __expf(vv[0] - lm) + __expf(vv[1] - lm)
                  + __expf(vv[2] - lm) + __expf(vv[3] - lm);
        pm[rq][b] = lm;
    }
    __syncthreads();
    if (tid < 32) {
        unsigned long long bb = lmax[0][tid];
#pragma unroll
        for (int q = 1; q < 8; ++q) bb = bb > lmax[q][tid] ? bb : lmax[q][tid];
        if (bb > amax[tid]) atomicMax(&amax[tid], bb);
        if (pairs) {
            float M = pm[0][tid], S = ps[0][tid];
#pragma unroll
            for (int q = 1; q < 8; ++q) {
                const float nm = fmaxf(M, pm[q][tid]);
                S = S * __expf(M - nm) + ps[q][tid] * __expf(pm[q][tid] - nm);
                M = nm;
            }
            float* pr = pairs + ((size_t)t * NTILE + blockIdx.x) * 64;
            pr[tid] = M;
            pr[32 + tid] = S;
        }
    }
}

// ---------------------------------------------------------------------------
// log-softmax. With pairs: combine 1000 per-tile (m,s) (8 KB) then ONE
// read+subtract+write sweep. Without: original fused 2-sweep fallback.
// ---------------------------------------------------------------------------
__global__ __launch_bounds__(256) void k_lsm(float* __restrict__ out,
                                             const float* __restrict__ pairs) {
    float* p = out + (size_t)blockIdx.x * VV;
    const int tid = threadIdx.x;
    __shared__ float sm[4], ss[4];

    float m = -1e30f, s = 0.0f;
    if (pairs) {
        const int b = blockIdx.x >> 6, t = blockIdx.x & 63;
        const float* pr = pairs + (size_t)t * NTILE * 64 + b;
        for (int tile = tid; tile < NTILE; tile += 256) {
            const float tm = pr[(size_t)tile * 64];
            const float ts = pr[(size_t)tile * 64 + 32];
            const float nm = fmaxf(m, tm);
            s = s * __expf(m - nm) + ts * __expf(tm - nm);
            m = nm;
        }
    } else {
        for (int i = tid * 4; i < VV; i += 1024) {
            const float4 v = *(const float4*)(p + i);
            const float cm = fmaxf(fmaxf(v.x, v.y), fmaxf(v.z, v.w));
            const float nm = fmaxf(m, cm);
            s = s * __expf(m - nm) + __expf(v.x - nm) + __expf(v.y - nm)
                                   + __expf(v.z - nm) + __expf(v.w - nm);
            m = nm;
        }
    }
#pragma unroll
    for (int off = 32; off > 0; off >>= 1) {
        const float om = __shfl_down(m, off, 64);
        const float os = __shfl_down(s, off, 64);
        const float nm = fmaxf(m, om);
        s = s * __expf(m - nm) + os * __expf(om - nm);
        m = nm;
    }
    if ((tid & 63) == 0) { sm[tid >> 6] = m; ss[tid >> 6] = s; }
    __syncthreads();
    float M = sm[0], S = ss[0];
#pragma unroll
    for (int w = 1; w < 4; ++w) {
        const float nm = fmaxf(M, sm[w]);
        S = S * __expf(M - nm) + ss[w] * __expf(sm[w] - nm);
        M = nm;
    }
    const float lz = M + __logf(S);
    for (int i = tid * 4; i < VV; i += 1024) {
        f32x4_ v = *(const f32x4_*)(p + i);
        v = v - lz;
        __builtin_nontemporal_store(v, (f32x4_*)(p + i));
    }
}

// ---------------------------------------------------------------------------
extern "C" void kernel_launch(void* const* d_in, const int* in_sizes, int n_in,
                              void* d_out, int out_size, void* d_ws, size_t ws_size,
                              hipStream_t stream) {
    const float* ctx  = (const float*)d_in[0];
    const float* emb  = (const float*)d_in[1];
    const float* Wih0 = (const float*)d_in[2];
    const float* Whh0 = (const float*)d_in[3];
    const float* bih0 = (const float*)d_in[4];
    const float* bhh0 = (const float*)d_in[5];
    const float* Wih1 = (const float*)d_in[6];
    const float* Whh1 = (const float*)d_in[7];
    const float* bih1 = (const float*)d_in[8];
    const float* bhh1 = (const float*)d_in[9];
    const float* Wout = (const float*)d_in[10];
    const float* bout = (const float*)d_in[11];

    float* out = (float*)d_out;
    float* ws  = (float*)d_ws;
    float* h0T[2] = { ws + OFF_H0T, ws + OFF_H0T + 16384 };
    float* h1T[2] = { ws + OFF_H1T, ws + OFF_H1T + 16384 };
    float* c0  = ws + OFF_C0;
    float* c1  = ws + OFF_C1;
    float* pc0 = ws + OFF_PC0;
    unsigned long long* amax = (unsigned long long*)(ws + OFF_AMAX);

    const size_t need_bytes = (size_t)(OFF_PAIRS + TT * NTILE * 64) * sizeof(float);
    float* pairs = (ws_size >= need_bytes) ? (ws + OFF_PAIRS) : nullptr;

    k_init<<<64, 256, 0, stream>>>(ws);
    k_pc0<<<128, 256, 0, stream>>>(Wih0, ctx, bih0, bhh0, pc0);

    for (int t = 0; t < TT; ++t) {
        const int pp = t & 1, nn = pp ^ 1;
        k_lstm<0><<<256, 256, 0, stream>>>(
            Wih0, Whh0, nullptr, h0T[pp], emb, amax, pc0, nullptr, nullptr,
            h0T[nn], c0, nullptr);
        k_lstm<1><<<256, 256, 0, stream>>>(
            Wih1, Whh1, h0T[nn], h1T[pp], emb, nullptr, nullptr, bih1, bhh1,
            h1T[nn], c1, amax);
        k_logits<<<1000, 256, 0, stream>>>(h1T[nn], Wout, bout, out, amax, pairs, t);
    }
    k_lsm<<<BB * TT, 256, 0, stream>>>(out, pairs);
}